// Round 15
// baseline (1713.766 us; speedup 1.0000x reference)
//
#include <hip/hip_runtime.h>
#include <hip/hip_bf16.h>
#include <hip/hip_fp16.h>

typedef __hip_bfloat16 bf16;
typedef _Float16 half8 __attribute__((ext_vector_type(8)));
typedef float f32x4 __attribute__((ext_vector_type(4)));

#define FDIM 128
#define SELF_W 2.0f
#define NGRAPH 64
#define DEG_SCALE 1048576.0f          // 2^20 fixed point for weighted degree
#define DEG_MASK  ((1ull<<44) - 1ull) // low 44 bits = degree sum, high 20 = count

__device__ __forceinline__ float b2f(bf16 v){ return __bfloat162float(v); }

__device__ __forceinline__ float rdf(const void* p, long long i, int f32){
  return f32 ? ((const float*)p)[i] : b2f(((const bf16*)p)[i]);
}
__device__ __forceinline__ int rdi(const void* p, long long i, int i64){
  return i64 ? (int)(((const long long*)p)[i]) : ((const int*)p)[i];
}

// fast tanh: exp+rcp (~8 VALU vs ~30 for libm tanhf); rel err ~2e-7
__device__ __forceinline__ float tanh_fast(float x){
  float ax = fabsf(x);
  float e  = __expf(-2.0f*ax);
  float r  = (1.0f - e) * __builtin_amdgcn_rcpf(1.0f + e);
  return copysignf(r, x);
}

__device__ __forceinline__ unsigned wave_incl_scan(unsigned v){
  int lane = threadIdx.x & 63;
  #pragma unroll
  for (int d = 1; d < 64; d <<= 1){
    unsigned t = __shfl_up(v, d, 64);
    if (lane >= d) v += t;
  }
  return v;
}

// Hierarchical monotonic grid barrier (R11-proven structure): 256 arrival
// counters (fan-out RMW, <=8 serialized per counter at 2048 blocks) + block-0
// parallel poll + single monotonic release word. ~2-4us/barrier vs ~50us flat.
// Monotonic round: no reset races; ctrs/release zeroed by memset pre-launch.
__device__ __forceinline__ void hsync(unsigned* ctrs, unsigned* release,
                                      unsigned nblk, unsigned round){
  __syncthreads();
  int tid = threadIdx.x;
  if (tid == 0)
    __hip_atomic_fetch_add(&ctrs[blockIdx.x & 255], 1u, __ATOMIC_RELEASE, __HIP_MEMORY_SCOPE_AGENT);
  if (blockIdx.x == 0){
    __shared__ unsigned red[256];
    for (;;){
      unsigned v = __hip_atomic_load(&ctrs[tid], __ATOMIC_ACQUIRE, __HIP_MEMORY_SCOPE_AGENT);
      red[tid] = v;
      __syncthreads();
      for (int s = 128; s > 0; s >>= 1){
        if (tid < s) red[tid] += red[tid + s];
        __syncthreads();
      }
      unsigned tot = red[0];
      __syncthreads();
      if (tot >= round*nblk) break;
      __builtin_amdgcn_s_sleep(2);
    }
    if (tid == 0)
      __hip_atomic_store(release, round, __ATOMIC_RELEASE, __HIP_MEMORY_SCOPE_AGENT);
  } else if (tid == 0){
    while (__hip_atomic_load(release, __ATOMIC_ACQUIRE, __HIP_MEMORY_SCOPE_AGENT) < round)
      __builtin_amdgcn_s_sleep(1);
  }
  __threadfence();
  __syncthreads();
}

// ---- GEMM tile (device fn): 64 rows x 128 @ W -> ROW-MAJOR fp16 [N][128] ----
template<int MODE>
__device__ __forceinline__ void gemm_tile(int tile, const void* __restrict__ in,
                                          const _Float16* __restrict__ WT,
                                          _Float16* __restrict__ outp, int N,
                                          int f32, _Float16* sout){
  int tid  = threadIdx.x;
  int wid  = tid >> 6, lane = tid & 63;
  int ln   = lane & 15, quad = lane >> 4;
  int row0 = tile * 64;
  int rowA = row0 + wid*16 + ln;
  int rA   = (rowA < N) ? rowA : (N > 0 ? N-1 : 0);

  half8 af[4];
  if (MODE == 1){
    const _Float16* src = (const _Float16*)in + (size_t)rA*FDIM + quad*8;
    #pragma unroll
    for (int kc = 0; kc < 4; kc++)
      af[kc] = *(const half8*)(src + kc*32);
  } else {
    if (f32){
      const float* src = (const float*)in + (size_t)rA*FDIM + quad*8;
      #pragma unroll
      for (int kc = 0; kc < 4; kc++){
        float4 a = *(const float4*)(src + kc*32);
        float4 b = *(const float4*)(src + kc*32 + 4);
        half8 h; h[0]=(_Float16)a.x; h[1]=(_Float16)a.y; h[2]=(_Float16)a.z; h[3]=(_Float16)a.w;
        h[4]=(_Float16)b.x; h[5]=(_Float16)b.y; h[6]=(_Float16)b.z; h[7]=(_Float16)b.w;
        af[kc] = h;
      }
    } else {
      const unsigned short* src = (const unsigned short*)in + (size_t)rA*FDIM + quad*8;
      #pragma unroll
      for (int kc = 0; kc < 4; kc++){
        ushort4 u0 = *(const ushort4*)(src + kc*32);
        ushort4 u1 = *(const ushort4*)(src + kc*32 + 4);
        half8 h;
        h[0]=(_Float16)__uint_as_float((unsigned)u0.x<<16);
        h[1]=(_Float16)__uint_as_float((unsigned)u0.y<<16);
        h[2]=(_Float16)__uint_as_float((unsigned)u0.z<<16);
        h[3]=(_Float16)__uint_as_float((unsigned)u0.w<<16);
        h[4]=(_Float16)__uint_as_float((unsigned)u1.x<<16);
        h[5]=(_Float16)__uint_as_float((unsigned)u1.y<<16);
        h[6]=(_Float16)__uint_as_float((unsigned)u1.z<<16);
        h[7]=(_Float16)__uint_as_float((unsigned)u1.w<<16);
        af[kc] = h;
      }
    }
  }

  f32x4 acc[8];
  #pragma unroll
  for (int nt = 0; nt < 8; nt++) acc[nt] = (f32x4){0.f,0.f,0.f,0.f};

  #pragma unroll
  for (int kc = 0; kc < 4; kc++){
    #pragma unroll
    for (int nt = 0; nt < 8; nt++){
      half8 bfr = *(const half8*)(WT + (size_t)(nt*16 + ln)*FDIM + kc*32 + quad*8);
      acc[nt] = __builtin_amdgcn_mfma_f32_16x16x32_f16(af[kc], bfr, acc[nt], 0, 0, 0);
    }
  }

  _Float16* so = sout + wid*2176;
  #pragma unroll
  for (int nt = 0; nt < 8; nt++)
    #pragma unroll
    for (int reg = 0; reg < 4; reg++)
      so[(quad*4 + reg)*136 + nt*16 + ln] = (_Float16)acc[nt][reg];
  __syncthreads();

  #pragma unroll
  for (int c = 0; c < 4; c++){
    int chunk = tid + c*256;
    int r = chunk >> 4, co = (chunk & 15)*8;
    int row = row0 + r;
    if (row < N){
      half8 v = *(const half8*)(sout + (r>>4)*2176 + (r&15)*136 + co);
      *(half8*)(outp + (size_t)row*FDIM + co) = v;
    }
  }
  __syncthreads();   // protect sout before next tile
}

// ---- ONE-PASS agg (device fn): 16 nodes/step, 16 lanes x 8 cols, row-major ----
__device__ __forceinline__ void agg_group(int grp, const _Float16* __restrict__ tp,
                                          const float* __restrict__ swv,
                                          const unsigned* __restrict__ off,
                                          const unsigned* __restrict__ epk,
                                          const float* __restrict__ bias,
                                          _Float16* __restrict__ hp, int N){
  int tid  = threadIdx.x;
  int wv   = tid >> 6, lane = tid & 63;
  int quad = lane >> 4, ql = lane & 15;
  int n = grp*16 + wv*4 + quad;
  bool valid = (n < N);
  int nn = valid ? n : 0;
  const _Float16* myt = tp + ql*8;

  float acc[8];
  {
    float sw = swv[nn];
    half8 sv = *(const half8*)(myt + (size_t)nn*FDIM);
    #pragma unroll
    for (int k = 0; k < 8; k++) acc[k] = sw * (float)sv[k];
  }

  unsigned beg = off[nn];
  unsigned end = valid ? off[nn+1] : beg;
  if (beg < end){
    uint4 p0 = *(const uint4*)(epk + beg);
    uint4 p1 = *(const uint4*)(epk + beg + 4);
    for (unsigned i = beg; i < end; i += 8){
      unsigned ni  = i + 8;
      unsigned pre = (ni < end) ? ni : beg;     // clamped prefetch (always valid)
      uint4 q0 = *(const uint4*)(epk + pre);
      uint4 q1 = *(const uint4*)(epk + pre + 4);
      unsigned vs[8] = {p0.x,p0.y,p0.z,p0.w,p1.x,p1.y,p1.z,p1.w};
      half8 tv[8];
      #pragma unroll
      for (int j = 0; j < 8; j++)
        tv[j] = *(const half8*)(myt + (size_t)(vs[j] & 0xffffu)*FDIM);
      #pragma unroll
      for (int j = 0; j < 8; j++){
        float w = (float)__builtin_bit_cast(_Float16, (unsigned short)(vs[j] >> 16));
        #pragma unroll
        for (int k = 0; k < 8; k++)
          acc[k] += w * (float)tv[j][k];
      }
      p0 = q0; p1 = q1;
    }
  }
  int cc = ql*8;
  float4 b0 = *(const float4*)(bias + cc);
  float4 b1 = *(const float4*)(bias + cc + 4);
  float bb[8] = {b0.x,b0.y,b0.z,b0.w,b1.x,b1.y,b1.z,b1.w};
  half8 out;
  #pragma unroll
  for (int k = 0; k < 8; k++)
    out[k] = (_Float16)tanh_fast(acc[k] + bb[k]);
  if (valid)
    *(half8*)(hp + (size_t)nn*FDIM + ql*8) = out;
}

struct PtrPack { const void* p[10]; };

// ======== mega v2: whole pipeline, 14 HIERARCHICAL barriers, UNCAPPED occupancy ========
// R8 mega failed on (a) flat barrier ~0.1us/block (690us) and (b) lb(256,2) occupancy
// cap. v2 fixes both: hsync ~2-4us/barrier; no min-waves bound (grid = occupancy query).
__global__ void k_mega2(
    PtrPack pk,
    const void* __restrict__ x, const void* __restrict__ ei,
    const void* __restrict__ bat, const void* __restrict__ ew,
    float* __restrict__ pf, _Float16* __restrict__ wt,
    unsigned long long* __restrict__ packed,
    float* __restrict__ dinv, float* __restrict__ swv,
    unsigned* __restrict__ off, unsigned* __restrict__ bsum,
    unsigned* __restrict__ rank, unsigned* __restrict__ epk,
    _Float16* __restrict__ th, _Float16* __restrict__ hh,
    float* __restrict__ pmax, float* __restrict__ psum,
    unsigned* __restrict__ gstart, void* __restrict__ outp,
    unsigned* __restrict__ ctrs, unsigned* __restrict__ release,
    int N, int E, int NB, unsigned Epad)
{
  __shared__ __align__(16) char smraw[4*16*136*2];   // 17408 B: gemm sout / pool / scan
  _Float16* sout = (_Float16*)smraw;
  __shared__ int s_cbig, s_codd;
  __shared__ unsigned swsh[8];

  int tid = threadIdx.x;
  const unsigned nblk = gridDim.x;
  unsigned gtid = blockIdx.x*256u + (unsigned)tid;
  const unsigned tot = nblk*256u;
  unsigned round = 0;
  #define HS() hsync(ctrs, release, nblk, ++round)

  // ---- P0: format probe (block-local) + params->pf/WT + packed init + gstart ----
  if (tid == 0){ s_cbig = 0; s_codd = 0; }
  __syncthreads();
  {
    const unsigned short* x16 = (const unsigned short*)x;
    const int* ei32 = (const int*)ei;
    for (int i = tid; i < 4096; i += 256){
      int e = (x16[i] >> 7) & 0xFF;
      if (e >= 134) atomicAdd(&s_cbig, 1);
    }
    for (int i = tid; i < 512; i += 256){
      if (ei32[2*i + 1] != 0) atomicAdd(&s_codd, 1);
    }
  }
  __syncthreads();
  const int f32 = (s_cbig >= 64) ? 1 : 0;
  const int i64 = (s_codd < 8)  ? 1 : 0;

  {
    const int sz[10]  = {16384,16384,16384,16384,128,128,128,128,256,1};
    const int dst[10] = {0,16384,32768,49152,65536,65664,65792,65920,66048,66304};
    for (unsigned i = gtid; i < 66305u; i += tot){
      int seg = 0, rem = (int)i;
      while (rem >= sz[seg]){ rem -= sz[seg]; seg++; }
      float v = rdf(pk.p[seg], rem, f32);
      pf[dst[seg] + rem] = v;
      if (seg < 4){
        int k = rem >> 7, n = rem & 127;
        wt[seg*16384 + n*128 + k] = (_Float16)v;
      }
    }
  }
  for (unsigned j = gtid; j < (unsigned)N; j += tot)
    packed[j] = (unsigned long long)(SELF_W * DEG_SCALE);
  if (blockIdx.x == 0 && tid <= NGRAPH){
    int lo = 0, hi = N;
    while (lo < hi){ int mid = (lo + hi) >> 1; if (rdi(bat, mid, i64) < tid) lo = mid + 1; else hi = mid; }
    gstart[tid] = (unsigned)lo;
  }
  HS();   // 1

  // ---- P1: weighted degree + rank (u64 atomics) ----
  for (unsigned e = gtid; e < (unsigned)E; e += tot){
    int d = rdi(ei, (long long)E + (long long)e, i64);
    if ((unsigned)d < (unsigned)N){
      float w = rdf(ew, e, f32);
      unsigned long long add = (1ull << 44) |
          (unsigned long long)__float2uint_rn(w * DEG_SCALE);
      rank[e] = (unsigned)(atomicAdd(&packed[d], add) >> 44);
    }
  }
  HS();   // 2

  // ---- P2: epk prefill + dinv/swv + per-chunk padded sums ----
  for (unsigned j = gtid; j < Epad; j += tot) epk[j] = 0u;
  if ((int)blockIdx.x < NB){
    int lane = tid & 63, wid = tid >> 6;
    int i0 = blockIdx.x*1024 + tid*4;
    unsigned tsum = 0u;
    #pragma unroll
    for (int j = 0; j < 4; j++){
      int i = i0 + j;
      if (i < N){
        unsigned long long pv = packed[i];
        tsum += ((unsigned)(pv >> 44) + 7u) & ~7u;
        float d = (float)(pv & DEG_MASK) * (1.0f / DEG_SCALE);
        float di = (d > 0.f) ? rsqrtf(d) : 0.f;
        dinv[i] = di;
        swv[i]  = di * di * SELF_W;
      }
    }
    #pragma unroll
    for (int d = 1; d < 64; d <<= 1) tsum += __shfl_down(tsum, d, 64);
    if (lane == 0) swsh[wid] = tsum;
    __syncthreads();
    if (tid == 0) bsum[blockIdx.x] = swsh[0] + swsh[1] + swsh[2] + swsh[3];
  }
  HS();   // 3

  // ---- P3: scan finalize -> off[] ----
  if ((int)blockIdx.x < NB){
    int lane = tid & 63, wid = tid >> 6;
    if (tid < 64){
      unsigned v = (tid < NB) ? bsum[tid] : 0u;
      unsigned isc = wave_incl_scan(v);
      if (tid == (int)blockIdx.x) swsh[4] = isc - v;
      if (tid == 63) swsh[5] = isc;
    }
    __syncthreads();
    int i0 = blockIdx.x*1024 + tid*4;
    unsigned v0=0u,v1=0u,v2=0u,v3=0u;
    if (i0+0 < N) v0 = ((unsigned)(packed[i0+0] >> 44) + 7u) & ~7u;
    if (i0+1 < N) v1 = ((unsigned)(packed[i0+1] >> 44) + 7u) & ~7u;
    if (i0+2 < N) v2 = ((unsigned)(packed[i0+2] >> 44) + 7u) & ~7u;
    if (i0+3 < N) v3 = ((unsigned)(packed[i0+3] >> 44) + 7u) & ~7u;
    unsigned tsum = v0+v1+v2+v3;
    unsigned isc = wave_incl_scan(tsum);
    if (lane == 63) swsh[wid] = isc;
    __syncthreads();
    unsigned wbase = 0u;
    #pragma unroll
    for (int w = 0; w < 4; w++) if (w < wid) wbase += swsh[w];
    unsigned ex = swsh[4] + wbase + (isc - tsum);
    if (i0+0 < N) off[i0+0] = ex;
    if (i0+1 < N) off[i0+1] = ex + v0;
    if (i0+2 < N) off[i0+2] = ex + v0 + v1;
    if (i0+3 < N) off[i0+3] = ex + v0 + v1 + v2;
    if ((int)blockIdx.x == NB-1 && tid == 0) off[N] = swsh[5];
  }
  HS();   // 4

  // ---- P4: bucket scatter (atomic-free) ----
  for (unsigned e = gtid; e < (unsigned)E; e += tot){
    int s_ = rdi(ei, (long long)e, i64);
    int d  = rdi(ei, (long long)E + (long long)e, i64);
    if ((unsigned)s_ >= (unsigned)N || (unsigned)d >= (unsigned)N) continue;
    unsigned pos = off[d] + rank[e];
    if (pos < Epad){
      float coef = dinv[s_] * rdf(ew, e, f32) * dinv[d];
      _Float16 ch = (_Float16)coef;
      unsigned cu = (unsigned)__builtin_bit_cast(unsigned short, ch);
      epk[pos] = ((unsigned)s_ & 0xffffu) | (cu << 16);
    }
  }
  HS();   // 5

  // ---- P5..P12: 4 x (GEMM -> barrier -> AGG -> barrier) ----
  const int ntile = (N + 63) >> 6;
  const int ng    = (N + 15) >> 4;
  #pragma unroll 1
  for (int l = 0; l < 4; l++){
    const _Float16* WTl = wt + (size_t)l*16384;
    if (l == 0){
      for (int t = blockIdx.x; t < ntile; t += (int)nblk)
        gemm_tile<0>(t, x, WTl, th, N, f32, sout);
    } else {
      for (int t = blockIdx.x; t < ntile; t += (int)nblk)
        gemm_tile<1>(t, hh, WTl, th, N, f32, sout);
    }
    HS(); // 6,8,10,12
    const float* bias = pf + 65536 + l*128;
    for (int g = blockIdx.x; g < ng; g += (int)nblk)
      agg_group(g, th, swv, off, epk, bias, hh, N);
    HS(); // 7,9,11,13
  }

  // ---- P13: pool partials (deterministic slots), row-major hh ----
  {
    float* shm = (float*)smraw;
    float* shs = shm + 256;
    for (int vb = blockIdx.x; vb < 16*NGRAPH; vb += (int)nblk){
      int g = vb >> 4, sub = vb & 15;
      int col = tid & 127, half_ = tid >> 7;
      const _Float16* hpp = hh + col;
      unsigned s0 = gstart[g], s1 = gstart[g+1];
      float m = -INFINITY, sm = 0.f;
      for (unsigned n = s0 + sub*2 + half_; n < s1; n += 32){
        float v = (float)hpp[(size_t)n*FDIM];
        m = fmaxf(m, v); sm += v;
      }
      shm[tid] = m; shs[tid] = sm;
      __syncthreads();
      if (half_ == 0){
        m  = fmaxf(m, shm[tid + 128]);
        sm += shs[tid + 128];
        int slot = (g*16 + sub)*128 + col;
        pmax[slot] = m;
        psum[slot] = sm;
      }
      __syncthreads();
    }
  }
  HS();   // 14

  // ---- P14: pool reduce + head ----
  if ((int)blockIdx.x < NGRAPH){
    int g = blockIdx.x;
    int col = tid & 127, sub = tid >> 7;
    unsigned cnt = gstart[g+1] - gstart[g];
    float val;
    if (sub == 0){
      float m = -INFINITY;
      #pragma unroll
      for (int j = 0; j < 16; j++) m = fmaxf(m, pmax[(g*16 + j)*128 + col]);
      val = (cnt > 0 && m > -INFINITY) ? m : 0.f;
    } else {
      float s = 0.f;
      #pragma unroll
      for (int j = 0; j < 16; j++) s += psum[(g*16 + j)*128 + col];
      val = s / (float)(cnt ? cnt : 1u);
    }
    int hcol = sub*128 + col;
    int hidx = NGRAPH + g*(2*FDIM) + hcol;
    if (f32) ((float*)outp)[hidx] = val;
    else     ((bf16*)outp)[hidx] = __float2bfloat16(val);

    float* red = (float*)smraw;
    red[hcol] = val * pf[66048 + hcol];
    __syncthreads();
    for (int s = 128; s > 0; s >>= 1){
      if (tid < s) red[tid] += red[tid + s];
      __syncthreads();
    }
    if (tid == 0){
      float o = red[0] + pf[66304];
      if (f32) ((float*)outp)[g] = o;
      else     ((bf16*)outp)[g] = __float2bfloat16(o);
    }
  }
  #undef HS
}

extern "C" void kernel_launch(void* const* d_in, const int* in_sizes, int n_in,
                              void* d_out, int out_size, void* d_ws, size_t ws_size,
                              hipStream_t stream){
  int N = in_sizes[0] / FDIM;   // x: [N,128]
  int E = in_sizes[3];          // edge_weight: [E]
  int NB = (N + 1023) / 1024;   // scan chunks (<=64 for N<=65536)
  unsigned Epad = (unsigned)E + 8u*(unsigned)N;

  char* p = (char*)d_ws;
  auto alloc = [&](size_t bytes){ char* r = p; p += (bytes + 255) & ~(size_t)255; return r; };
  float*     pf     = (float*)    alloc((size_t)(66305 + 64)*4);
  _Float16*  wt     = (_Float16*) alloc((size_t)4*FDIM*FDIM*2);
  unsigned long long* packed = (unsigned long long*)alloc((size_t)N*8);
  float*     dinv   = (float*)    alloc((size_t)N*4);
  float*     swv    = (float*)    alloc((size_t)N*4);
  unsigned*  off    = (unsigned*) alloc((size_t)(N+1)*4);
  unsigned*  bsum   = (unsigned*) alloc((size_t)128*4);
  unsigned*  rank   = (unsigned*) alloc((size_t)E*4);
  unsigned*  epk    = (unsigned*) alloc((size_t)Epad*4);
  _Float16*  th     = (_Float16*) alloc((size_t)N*FDIM*2);  // row-major [N][128]
  _Float16*  hh     = (_Float16*) alloc((size_t)N*FDIM*2);  // row-major [N][128]
  float*     pmax   = (float*)    alloc((size_t)NGRAPH*16*128*4);
  float*     psum   = (float*)    alloc((size_t)NGRAPH*16*128*4);
  unsigned*  gstart = (unsigned*) alloc((size_t)(NGRAPH+1)*4);
  unsigned*  hb     = (unsigned*) alloc((size_t)(256 + 64)*4);   // ctrs[256] + release

  hipMemsetAsync(hb, 0, (256 + 64)*4, stream);   // ws is poisoned

  unsigned* release = hb + 256;

  PtrPack pk;
  pk.p[0]=d_in[4]; pk.p[1]=d_in[6]; pk.p[2]=d_in[8]; pk.p[3]=d_in[10];
  pk.p[4]=d_in[5]; pk.p[5]=d_in[7]; pk.p[6]=d_in[9]; pk.p[7]=d_in[11];
  pk.p[8]=d_in[12]; pk.p[9]=d_in[13];

  // grid = co-residency capacity (occupancy query; cooperative launch enforces)
  int occ = 0, nblk = 512;
  if (hipOccupancyMaxActiveBlocksPerMultiprocessor(&occ, k_mega2, 256, 0) == hipSuccess && occ > 0)
    nblk = occ * 256;            // 256 CUs on MI355X
  if (nblk > 2048) nblk = 2048;  // barrier fan-out sanity (8 blocks/counter)
  if (nblk < 64) nblk = 64;      // scan/pool phases need >= max(NB,64)

  const void* xp = d_in[0];  const void* eip = d_in[1];
  const void* batp = d_in[2]; const void* ewp = d_in[3];
  void* outp = d_out;
  void* kargs[] = {
    (void*)&pk, (void*)&xp, (void*)&eip, (void*)&batp, (void*)&ewp,
    (void*)&pf, (void*)&wt, (void*)&packed, (void*)&dinv, (void*)&swv,
    (void*)&off, (void*)&bsum, (void*)&rank, (void*)&epk,
    (void*)&th, (void*)&hh, (void*)&pmax, (void*)&psum,
    (void*)&gstart, (void*)&outp, (void*)&hb, (void*)&release,
    (void*)&N, (void*)&E, (void*)&NB, (void*)&Epad
  };
  hipError_t err = hipLaunchCooperativeKernel((void*)k_mega2, dim3(nblk), dim3(256),
                                              kargs, 0, stream);
  if (err != hipSuccess){
    // fallback: plain launch with occupancy-derived grid (capacity co-residency)
    k_mega2<<<nblk, 256, 0, stream>>>(pk, xp, eip, batp, ewp,
                                      pf, wt, packed, dinv, swv, off, bsum, rank, epk,
                                      th, hh, pmax, psum, gstart, outp, hb, release,
                                      N, E, NB, Epad);
  }
}

// Round 16
// 460.695 us; speedup vs baseline: 3.7200x; 3.7200x over previous
//
#include <hip/hip_runtime.h>
#include <hip/hip_bf16.h>
#include <hip/hip_fp16.h>

typedef __hip_bfloat16 bf16;
typedef _Float16 half8 __attribute__((ext_vector_type(8)));
typedef float f32x4 __attribute__((ext_vector_type(4)));

#define FDIM 128
#define SELF_W 2.0f
#define NGRAPH 64
#define DEG_SCALE 1048576.0f          // 2^20 fixed point for weighted degree
#define DEG_MASK  ((1ull<<44) - 1ull) // low 44 bits = degree sum, high 20 = count

__device__ __forceinline__ float b2f(bf16 v){ return __bfloat162float(v); }

__device__ __forceinline__ float rdf(const void* p, long long i, int f32){
  return f32 ? ((const float*)p)[i] : b2f(((const bf16*)p)[i]);
}
__device__ __forceinline__ int rdi(const void* p, long long i, int i64){
  return i64 ? (int)(((const long long*)p)[i]) : ((const int*)p)[i];
}

// fast tanh: exp+rcp (~8 VALU vs ~30 for libm tanhf); rel err ~2e-7
__device__ __forceinline__ float tanh_fast(float x){
  float ax = fabsf(x);
  float e  = __expf(-2.0f*ax);
  float r  = (1.0f - e) * __builtin_amdgcn_rcpf(1.0f + e);
  return copysignf(r, x);
}

// fused setup: per-block local input-format probe; params -> pf(f32) + WT(fp16,T);
// packed init; graph bounds (tail block); block 0 publishes flags.
struct PtrPack { const void* p[10]; };
__global__ __launch_bounds__(256) void k_setup(PtrPack pk, float* __restrict__ pf,
                                               _Float16* __restrict__ wt,
                                               unsigned long long* __restrict__ packed,
                                               const void* __restrict__ bat,
                                               unsigned* __restrict__ gstart,
                                               const unsigned short* __restrict__ x16,
                                               const int* __restrict__ ei32,
                                               int* __restrict__ flags_out,
                                               int N){
  __shared__ int cbig, codd, sf32, si64;
  int tid = threadIdx.x;
  if (tid == 0){ cbig = 0; codd = 0; }
  __syncthreads();
  for (int i = tid; i < 4096; i += 256){
    int e = (x16[i] >> 7) & 0xFF;
    if (e >= 134) atomicAdd(&cbig, 1);
  }
  for (int i = tid; i < 512; i += 256){
    if (ei32[2*i + 1] != 0) atomicAdd(&codd, 1);
  }
  __syncthreads();
  if (tid == 0){
    sf32 = (cbig >= 64) ? 1 : 0;   // floats are f32
    si64 = (codd < 8)  ? 1 : 0;    // ints are int64
    if (blockIdx.x == 0){ flags_out[0] = sf32; flags_out[1] = si64; }
  }
  __syncthreads();
  int f32 = sf32, i64 = si64;

  const int sz[10]  = {16384,16384,16384,16384,128,128,128,128,256,1};
  const int dst[10] = {0,16384,32768,49152,65536,65664,65792,65920,66048,66304};
  int i = blockIdx.x*blockDim.x + tid;
  if (i < 66305){
    int seg = 0, rem = i;
    while (rem >= sz[seg]){ rem -= sz[seg]; seg++; }
    float v = rdf(pk.p[seg], rem, f32);
    pf[dst[seg] + rem] = v;
    if (seg < 4){                     // W[l][k][n] -> WT[l][n][k] fp16
      int k = rem >> 7, n = rem & 127;
      wt[seg*16384 + n*128 + k] = (_Float16)v;
    }
  }
  // packed degree init (grid-stride)
  int stride = gridDim.x*blockDim.x;
  for (int j = i; j < N; j += stride)
    packed[j] = (unsigned long long)(SELF_W * DEG_SCALE);
  // graph bounds in last block (batch is sorted)
  if (blockIdx.x == gridDim.x - 1){
    __shared__ unsigned s[NGRAPH+1];
    int g = tid;
    if (g <= NGRAPH){
      int lo = 0, hi = N;
      while (lo < hi){ int mid = (lo + hi) >> 1; if (rdi(bat, mid, i64) < g) lo = mid + 1; else hi = mid; }
      s[g] = (unsigned)lo;
    }
    __syncthreads();
    if (g <= NGRAPH) gstart[g] = s[g];
  }
}

// edge pass 1: 2 edges/thread, independent u64 atomics (latency overlap).
// ~30us measured (R14 probe) — fabric-atomic throughput floor, not contention.
__global__ void k_edge_deg(const void* __restrict__ ei, const void* __restrict__ ew,
                           unsigned long long* __restrict__ packed,
                           unsigned* __restrict__ rank,
                           int E, int N, const int* __restrict__ flags){
  int e0 = 2*(blockIdx.x*blockDim.x + threadIdx.x);
  if (e0 >= E) return;
  int i64 = flags[1], f32 = flags[0];
  int e1 = e0 + 1;
  bool h1 = (e1 < E);
  int d0 = rdi(ei, (long long)E + e0, i64);
  int d1 = h1 ? rdi(ei, (long long)E + e1, i64) : 0;
  float w0 = rdf(ew, e0, f32);
  float w1 = h1 ? rdf(ew, e1, f32) : 0.f;
  unsigned r0 = 0u, r1 = 0u;
  if ((unsigned)d0 < (unsigned)N){
    unsigned long long add = (1ull << 44) |
        (unsigned long long)__float2uint_rn(w0 * DEG_SCALE);
    r0 = (unsigned)(atomicAdd(&packed[d0], add) >> 44);
  }
  if (h1 && (unsigned)d1 < (unsigned)N){
    unsigned long long add = (1ull << 44) |
        (unsigned long long)__float2uint_rn(w1 * DEG_SCALE);
    r1 = (unsigned)(atomicAdd(&packed[d1], add) >> 44);
  }
  rank[e0] = r0;
  if (h1) rank[e1] = r1;
}

__device__ __forceinline__ unsigned wave_incl_scan(unsigned v){
  int lane = threadIdx.x & 63;
  #pragma unroll
  for (int d = 1; d < 64; d <<= 1){
    unsigned t = __shfl_up(v, d, 64);
    if (lane >= d) v += t;
  }
  return v;
}

// scan phase A: per-block PADDED-count sum -> bsum; fused dinv + self-weight;
// also prefills epk (grid-stride).
__global__ __launch_bounds__(256) void k_scan_pre(const unsigned long long* __restrict__ packed,
                                                  float* __restrict__ dinv,
                                                  float* __restrict__ swv,
                                                  unsigned* __restrict__ bsum,
                                                  unsigned* __restrict__ epk, unsigned Epad,
                                                  int N){
  __shared__ unsigned wsh[4];
  int tid = threadIdx.x, lane = tid & 63, wid = tid >> 6;
  unsigned gid = blockIdx.x*blockDim.x + tid, gstr = gridDim.x*blockDim.x;
  for (unsigned j = gid; j < Epad; j += gstr) epk[j] = 0u;
  int i0 = blockIdx.x*1024 + tid*4;
  unsigned tsum = 0u;
  #pragma unroll
  for (int j = 0; j < 4; j++){
    int i = i0 + j;
    if (i < N){
      unsigned long long pv = packed[i];
      tsum += ((unsigned)(pv >> 44) + 7u) & ~7u;
      float d = (float)(pv & DEG_MASK) * (1.0f / DEG_SCALE);
      float di = (d > 0.f) ? rsqrtf(d) : 0.f;
      dinv[i] = di;
      swv[i]  = di * di * SELF_W;
    }
  }
  #pragma unroll
  for (int d = 1; d < 64; d <<= 1) tsum += __shfl_down(tsum, d, 64);
  if (lane == 0) wsh[wid] = tsum;
  __syncthreads();
  if (tid == 0) bsum[blockIdx.x] = wsh[0] + wsh[1] + wsh[2] + wsh[3];
}

// scan phase B+C fused.
__global__ __launch_bounds__(256) void k_scan_fin(const unsigned long long* __restrict__ packed,
                                                  const unsigned* __restrict__ bsum,
                                                  unsigned* __restrict__ off, int N, int NB){
  __shared__ unsigned wsh[4];
  __shared__ unsigned sbase, stot;
  int tid = threadIdx.x, lane = tid & 63, wid = tid >> 6;
  if (tid < 64){
    unsigned v = (tid < NB) ? bsum[tid] : 0u;
    unsigned isc = wave_incl_scan(v);
    if (tid == (int)blockIdx.x) sbase = isc - v;
    if (tid == 63) stot = isc;
  }
  __syncthreads();
  int i0 = blockIdx.x*1024 + tid*4;
  unsigned v0=0u,v1=0u,v2=0u,v3=0u;
  if (i0+0 < N) v0 = ((unsigned)(packed[i0+0] >> 44) + 7u) & ~7u;
  if (i0+1 < N) v1 = ((unsigned)(packed[i0+1] >> 44) + 7u) & ~7u;
  if (i0+2 < N) v2 = ((unsigned)(packed[i0+2] >> 44) + 7u) & ~7u;
  if (i0+3 < N) v3 = ((unsigned)(packed[i0+3] >> 44) + 7u) & ~7u;
  unsigned tsum = v0+v1+v2+v3;
  unsigned isc = wave_incl_scan(tsum);
  if (lane == 63) wsh[wid] = isc;
  __syncthreads();
  unsigned wbase = 0u;
  #pragma unroll
  for (int w = 0; w < 4; w++) if (w < wid) wbase += wsh[w];
  unsigned ex = sbase + wbase + (isc - tsum);
  if (i0+0 < N) off[i0+0] = ex;
  if (i0+1 < N) off[i0+1] = ex + v0;
  if (i0+2 < N) off[i0+2] = ex + v0 + v1;
  if (i0+3 < N) off[i0+3] = ex + v0 + v1 + v2;
  if (blockIdx.x == gridDim.x - 1 && tid == 0) off[N] = stot;
}

// edge pass 2: atomic-free scatter; pack (u16 src | fp16 coef).
__global__ void k_bucket(const void* __restrict__ ei, const void* __restrict__ ew,
                         const float* __restrict__ dinv,
                         const unsigned* __restrict__ off,
                         const unsigned* __restrict__ rank,
                         unsigned* __restrict__ epk,
                         int E, unsigned Epad, int N, const int* __restrict__ flags){
  int e0 = 2*(blockIdx.x*blockDim.x + threadIdx.x);
  if (e0 >= E) return;
  int i64 = flags[1], f32 = flags[0];
  #pragma unroll
  for (int j = 0; j < 2; j++){
    int e = e0 + j;
    if (e >= E) break;
    int s_ = rdi(ei, e, i64);
    int d  = rdi(ei, (long long)E + e, i64);
    if ((unsigned)s_ >= (unsigned)N || (unsigned)d >= (unsigned)N) continue;
    unsigned pos = off[d] + rank[e];
    if (pos < Epad){
      float coef = dinv[s_] * rdf(ew, e, f32) * dinv[d];
      _Float16 ch = (_Float16)coef;
      unsigned cu = (unsigned)__builtin_bit_cast(unsigned short, ch);
      epk[pos] = ((unsigned)s_ & 0xffffu) | (cu << 16);
    }
  }
}

// MFMA GEMM: t = in[N,128] @ W; ROW-MAJOR fp16 output [N][128].
// MODE 0: raw x dense (flag-aware). MODE 1: fp16 row-major.
template<int MODE>
__global__ __launch_bounds__(256) void k_gemm(const void* __restrict__ in,
                                              const _Float16* __restrict__ WT,
                                              _Float16* __restrict__ outp, int N,
                                              const int* __restrict__ flags){
  __shared__ _Float16 sout[4*16*136];   // [wave][16 rows][128+8 cols]
  int tid  = threadIdx.x;
  int wid  = tid >> 6, lane = tid & 63;
  int ln   = lane & 15, quad = lane >> 4;
  int row0 = blockIdx.x * 64;
  int rowA = row0 + wid*16 + ln;
  int rA   = (rowA < N) ? rowA : (N > 0 ? N-1 : 0);

  half8 af[4];
  if (MODE == 1){
    const _Float16* src = (const _Float16*)in + (size_t)rA*FDIM + quad*8;
    #pragma unroll
    for (int kc = 0; kc < 4; kc++)
      af[kc] = *(const half8*)(src + kc*32);
  } else {
    if (flags[0]){
      const float* src = (const float*)in + (size_t)rA*FDIM + quad*8;
      #pragma unroll
      for (int kc = 0; kc < 4; kc++){
        float4 a = *(const float4*)(src + kc*32);
        float4 b = *(const float4*)(src + kc*32 + 4);
        half8 h; h[0]=(_Float16)a.x; h[1]=(_Float16)a.y; h[2]=(_Float16)a.z; h[3]=(_Float16)a.w;
        h[4]=(_Float16)b.x; h[5]=(_Float16)b.y; h[6]=(_Float16)b.z; h[7]=(_Float16)b.w;
        af[kc] = h;
      }
    } else {
      const unsigned short* src = (const unsigned short*)in + (size_t)rA*FDIM + quad*8;
      #pragma unroll
      for (int kc = 0; kc < 4; kc++){
        ushort4 u0 = *(const ushort4*)(src + kc*32);
        ushort4 u1 = *(const ushort4*)(src + kc*32 + 4);
        half8 h;
        h[0]=(_Float16)__uint_as_float((unsigned)u0.x<<16);
        h[1]=(_Float16)__uint_as_float((unsigned)u0.y<<16);
        h[2]=(_Float16)__uint_as_float((unsigned)u0.z<<16);
        h[3]=(_Float16)__uint_as_float((unsigned)u0.w<<16);
        h[4]=(_Float16)__uint_as_float((unsigned)u1.x<<16);
        h[5]=(_Float16)__uint_as_float((unsigned)u1.y<<16);
        h[6]=(_Float16)__uint_as_float((unsigned)u1.z<<16);
        h[7]=(_Float16)__uint_as_float((unsigned)u1.w<<16);
        af[kc] = h;
      }
    }
  }

  f32x4 acc[8];
  #pragma unroll
  for (int nt = 0; nt < 8; nt++) acc[nt] = (f32x4){0.f,0.f,0.f,0.f};

  #pragma unroll
  for (int kc = 0; kc < 4; kc++){
    #pragma unroll
    for (int nt = 0; nt < 8; nt++){
      half8 bf = *(const half8*)(WT + (size_t)(nt*16 + ln)*FDIM + kc*32 + quad*8);
      acc[nt] = __builtin_amdgcn_mfma_f32_16x16x32_f16(af[kc], bf, acc[nt], 0, 0, 0);
    }
  }

  _Float16* so = sout + wid*2176;
  #pragma unroll
  for (int nt = 0; nt < 8; nt++)
    #pragma unroll
    for (int reg = 0; reg < 4; reg++)
      so[(quad*4 + reg)*136 + nt*16 + ln] = (_Float16)acc[nt][reg];
  __syncthreads();

  #pragma unroll
  for (int c = 0; c < 4; c++){
    int chunk = tid + c*256;
    int r = chunk >> 4, co = (chunk & 15)*8;
    int row = row0 + r;
    if (row < N){
      half8 v = *(const half8*)(sout + (r>>4)*2176 + (r&15)*136 + co);
      *(half8*)(outp + (size_t)row*FDIM + co) = v;   // row-major store
    }
  }
}

// ONE-PASS aggregation (row-major table): wave = 4 nodes, 16 lanes x 8 cols.
// Per edge: quad's 16 lanes fetch one full 256B row (coalesced); fabric-bound.
__global__ __launch_bounds__(256) void k_agg(const _Float16* __restrict__ tp,
                                             const float* __restrict__ swv,
                                             const unsigned* __restrict__ off,
                                             const unsigned* __restrict__ epk,
                                             const float* __restrict__ bias,
                                             _Float16* __restrict__ hp,
                                             int N){
  int tid  = threadIdx.x;
  int wv   = tid >> 6, lane = tid & 63;
  int quad = lane >> 4, ql = lane & 15;
  int n = blockIdx.x*16 + wv*4 + quad;
  bool valid = (n < N);
  int nn = valid ? n : 0;
  const _Float16* myt = tp + ql*8;     // lane's 8-col slice base

  float acc[8];
  {
    float sw = swv[nn];
    half8 sv = *(const half8*)(myt + (size_t)nn*FDIM);
    #pragma unroll
    for (int k = 0; k < 8; k++) acc[k] = sw * (float)sv[k];
  }

  unsigned beg = off[nn];
  unsigned end = valid ? off[nn+1] : beg;
  if (beg < end){
    uint4 p0 = *(const uint4*)(epk + beg);
    uint4 p1 = *(const uint4*)(epk + beg + 4);
    for (unsigned i = beg; i < end; i += 8){
      unsigned ni  = i + 8;
      unsigned pre = (ni < end) ? ni : beg;     // clamped prefetch (always valid)
      uint4 q0 = *(const uint4*)(epk + pre);
      uint4 q1 = *(const uint4*)(epk + pre + 4);
      unsigned vs[8] = {p0.x,p0.y,p0.z,p0.w,p1.x,p1.y,p1.z,p1.w};
      half8 tv[8];
      #pragma unroll
      for (int j = 0; j < 8; j++)
        tv[j] = *(const half8*)(myt + (size_t)(vs[j] & 0xffffu)*FDIM);
      #pragma unroll
      for (int j = 0; j < 8; j++){
        float w = (float)__builtin_bit_cast(_Float16, (unsigned short)(vs[j] >> 16));
        #pragma unroll
        for (int k = 0; k < 8; k++)
          acc[k] += w * (float)tv[j][k];
      }
      p0 = q0; p1 = q1;
    }
  }
  int cc = ql*8;
  float4 b0 = *(const float4*)(bias + cc);
  float4 b1 = *(const float4*)(bias + cc + 4);
  float bb[8] = {b0.x,b0.y,b0.z,b0.w,b1.x,b1.y,b1.z,b1.w};
  half8 out;
  #pragma unroll
  for (int k = 0; k < 8; k++)
    out[k] = (_Float16)tanh_fast(acc[k] + bb[k]);
  if (valid)
    *(half8*)(hp + (size_t)nn*FDIM + ql*8) = out;
}

// MERGED pool + head: 64 blocks (one per graph). Each block reduces its graph's
// rows (max+sum per col) directly from row-major hh, writes hidden, head dot.
// Replaces pool_part+pool_out: -1 boundary, -512KB partial round-trip.
__global__ __launch_bounds__(256) void k_pool(const _Float16* __restrict__ hp,
                                              const unsigned* __restrict__ gstart,
                                              const float* __restrict__ Wout,
                                              const float* __restrict__ bout,
                                              void* __restrict__ outp,
                                              const int* __restrict__ flags){
  int g = blockIdx.x, tid = threadIdx.x;
  int col = tid & 127, half_ = tid >> 7;   // 2 threads per column
  unsigned s0 = gstart[g], s1 = gstart[g+1];
  unsigned cnt = s1 - s0;

  float m = -INFINITY, sm = 0.f;
  const _Float16* hpp = hp + col;
  for (unsigned n = s0 + half_; n < s1; n += 2){
    float v = (float)hpp[(size_t)n*FDIM];
    m = fmaxf(m, v); sm += v;
  }
  __shared__ float shm[256], shs[256];
  shm[tid] = m; shs[tid] = sm;
  __syncthreads();

  __shared__ float red[256];
  if (half_ == 0){
    m  = fmaxf(m, shm[tid + 128]);
    sm += shs[tid + 128];
    float vmax  = (cnt > 0 && m > -INFINITY) ? m : 0.f;   // empty-graph guard
    float vmean = sm / (float)(cnt ? cnt : 1u);
    int f32out = flags[0];
    int hbase = NGRAPH + g*(2*FDIM);
    if (f32out){
      ((float*)outp)[hbase + col]        = vmax;
      ((float*)outp)[hbase + 128 + col]  = vmean;
    } else {
      ((bf16*)outp)[hbase + col]         = __float2bfloat16(vmax);
      ((bf16*)outp)[hbase + 128 + col]   = __float2bfloat16(vmean);
    }
    red[col]       = vmax  * Wout[col];
    red[col + 128] = vmean * Wout[col + 128];
  }
  __syncthreads();
  for (int s = 128; s > 0; s >>= 1){
    if (tid < s) red[tid] += red[tid + s];
    __syncthreads();
  }
  if (tid == 0){
    float o = red[0] + bout[0];
    if (flags[0]) ((float*)outp)[g] = o;
    else          ((bf16*)outp)[g] = __float2bfloat16(o);
  }
}

extern "C" void kernel_launch(void* const* d_in, const int* in_sizes, int n_in,
                              void* d_out, int out_size, void* d_ws, size_t ws_size,
                              hipStream_t stream){
  int N = in_sizes[0] / FDIM;   // x: [N,128]
  int E = in_sizes[3];          // edge_weight: [E]
  int NB = (N + 1023) / 1024;
  unsigned Epad = (unsigned)E + 8u*(unsigned)N;

  char* p = (char*)d_ws;
  auto alloc = [&](size_t bytes){ char* r = p; p += (bytes + 255) & ~(size_t)255; return r; };
  int*       flags  = (int*)      alloc(16);
  float*     pf     = (float*)    alloc((size_t)(66305 + 64)*4);
  _Float16*  wt     = (_Float16*) alloc((size_t)4*FDIM*FDIM*2);
  unsigned long long* packed = (unsigned long long*)alloc((size_t)N*8);
  float*     dinv   = (float*)    alloc((size_t)N*4);
  float*     swv    = (float*)    alloc((size_t)N*4);
  unsigned*  off    = (unsigned*) alloc((size_t)(N+1)*4);
  unsigned*  bsum   = (unsigned*) alloc((size_t)128*4);
  unsigned*  rank   = (unsigned*) alloc((size_t)E*4);
  unsigned*  epk    = (unsigned*) alloc((size_t)Epad*4);
  _Float16*  th     = (_Float16*) alloc((size_t)N*FDIM*2);  // row-major [N][128]
  _Float16*  hh     = (_Float16*) alloc((size_t)N*FDIM*2);  // row-major [N][128]
  unsigned*  gstart = (unsigned*) alloc((size_t)(NGRAPH+1)*4);

  float* bf_[4] = {pf + 65536, pf + 65664, pf + 65792, pf + 65920};
  float* Woutf  = pf + 66048;
  float* boutf  = pf + 66304;

  PtrPack pk;
  pk.p[0]=d_in[4]; pk.p[1]=d_in[6]; pk.p[2]=d_in[8]; pk.p[3]=d_in[10];
  pk.p[4]=d_in[5]; pk.p[5]=d_in[7]; pk.p[6]=d_in[9]; pk.p[7]=d_in[11];
  pk.p[8]=d_in[12]; pk.p[9]=d_in[13];
  k_setup<<<(66305 + 255)/256, 256, 0, stream>>>(pk, pf, wt, packed, d_in[2], gstart,
                                                 (const unsigned short*)d_in[0],
                                                 (const int*)d_in[1], flags, N);
  int gE2 = (E + 511)/512;
  k_edge_deg<<<gE2, 256, 0, stream>>>(d_in[1], d_in[3], packed, rank, E, N, flags);
  k_scan_pre<<<NB, 256, 0, stream>>>(packed, dinv, swv, bsum, epk, Epad, N);
  k_scan_fin<<<NB, 256, 0, stream>>>(packed, bsum, off, N, NB);
  k_bucket<<<gE2, 256, 0, stream>>>(d_in[1], d_in[3], dinv, off, rank, epk, E, Epad, N, flags);

  int gG = (N + 63)/64;
  int gA = (N + 15)/16;

  k_gemm<0><<<gG, 256, 0, stream>>>(d_in[0], wt + 0*16384, th, N, flags);
  k_agg<<<gA, 256, 0, stream>>>(th, swv, off, epk, bf_[0], hh, N);
  for (int l = 1; l < 4; l++){
    k_gemm<1><<<gG, 256, 0, stream>>>(hh, wt + (size_t)l*16384, th, N, flags);
    k_agg<<<gA, 256, 0, stream>>>(th, swv, off, epk, bf_[l], hh, N);
  }

  k_pool<<<NGRAPH, 256, 0, stream>>>(hh, gstart, Woutf, boutf, d_out, flags);
}

// Round 17
// 362.280 us; speedup vs baseline: 4.7305x; 1.2717x over previous
//
#include <hip/hip_runtime.h>
#include <hip/hip_bf16.h>
#include <hip/hip_fp16.h>

typedef __hip_bfloat16 bf16;
typedef _Float16 half8 __attribute__((ext_vector_type(8)));
typedef float f32x4 __attribute__((ext_vector_type(4)));

#define FDIM 128
#define SELF_W 2.0f
#define NGRAPH 64
#define DEG_SCALE 1048576.0f          // 2^20 fixed point for weighted degree
#define DEG_MASK  ((1ull<<44) - 1ull) // low 44 bits = degree sum, high 20 = count

__device__ __forceinline__ float b2f(bf16 v){ return __bfloat162float(v); }

__device__ __forceinline__ float rdf(const void* p, long long i, int f32){
  return f32 ? ((const float*)p)[i] : b2f(((const bf16*)p)[i]);
}
__device__ __forceinline__ int rdi(const void* p, long long i, int i64){
  return i64 ? (int)(((const long long*)p)[i]) : ((const int*)p)[i];
}

// fast tanh: exp+rcp (~8 VALU vs ~30 for libm tanhf); rel err ~2e-7
__device__ __forceinline__ float tanh_fast(float x){
  float ax = fabsf(x);
  float e  = __expf(-2.0f*ax);
  float r  = (1.0f - e) * __builtin_amdgcn_rcpf(1.0f + e);
  return copysignf(r, x);
}

// fused setup: per-block local input-format probe; params -> pf(f32) + WT(fp16,T);
// packed init; graph bounds (tail block); block 0 publishes flags.
struct PtrPack { const void* p[10]; };
__global__ __launch_bounds__(256) void k_setup(PtrPack pk, float* __restrict__ pf,
                                               _Float16* __restrict__ wt,
                                               unsigned long long* __restrict__ packed,
                                               const void* __restrict__ bat,
                                               unsigned* __restrict__ gstart,
                                               const unsigned short* __restrict__ x16,
                                               const int* __restrict__ ei32,
                                               int* __restrict__ flags_out,
                                               int N){
  __shared__ int cbig, codd, sf32, si64;
  int tid = threadIdx.x;
  if (tid == 0){ cbig = 0; codd = 0; }
  __syncthreads();
  for (int i = tid; i < 4096; i += 256){
    int e = (x16[i] >> 7) & 0xFF;
    if (e >= 134) atomicAdd(&cbig, 1);
  }
  for (int i = tid; i < 512; i += 256){
    if (ei32[2*i + 1] != 0) atomicAdd(&codd, 1);
  }
  __syncthreads();
  if (tid == 0){
    sf32 = (cbig >= 64) ? 1 : 0;   // floats are f32
    si64 = (codd < 8)  ? 1 : 0;    // ints are int64
    if (blockIdx.x == 0){ flags_out[0] = sf32; flags_out[1] = si64; }
  }
  __syncthreads();
  int f32 = sf32, i64 = si64;

  const int sz[10]  = {16384,16384,16384,16384,128,128,128,128,256,1};
  const int dst[10] = {0,16384,32768,49152,65536,65664,65792,65920,66048,66304};
  int i = blockIdx.x*blockDim.x + tid;
  if (i < 66305){
    int seg = 0, rem = i;
    while (rem >= sz[seg]){ rem -= sz[seg]; seg++; }
    float v = rdf(pk.p[seg], rem, f32);
    pf[dst[seg] + rem] = v;
    if (seg < 4){                     // W[l][k][n] -> WT[l][n][k] fp16
      int k = rem >> 7, n = rem & 127;
      wt[seg*16384 + n*128 + k] = (_Float16)v;
    }
  }
  // packed degree init (grid-stride)
  int stride = gridDim.x*blockDim.x;
  for (int j = i; j < N; j += stride)
    packed[j] = (unsigned long long)(SELF_W * DEG_SCALE);
  // graph bounds in last block (batch is sorted)
  if (blockIdx.x == gridDim.x - 1){
    __shared__ unsigned s[NGRAPH+1];
    int g = tid;
    if (g <= NGRAPH){
      int lo = 0, hi = N;
      while (lo < hi){ int mid = (lo + hi) >> 1; if (rdi(bat, mid, i64) < g) lo = mid + 1; else hi = mid; }
      s[g] = (unsigned)lo;
    }
    __syncthreads();
    if (g <= NGRAPH) gstart[g] = s[g];
  }
}

// edge pass 1: 2 edges/thread, independent u64 atomics (latency overlap).
__global__ void k_edge_deg(const void* __restrict__ ei, const void* __restrict__ ew,
                           unsigned long long* __restrict__ packed,
                           unsigned* __restrict__ rank,
                           int E, int N, const int* __restrict__ flags){
  int e0 = 2*(blockIdx.x*blockDim.x + threadIdx.x);
  if (e0 >= E) return;
  int i64 = flags[1], f32 = flags[0];
  int e1 = e0 + 1;
  bool h1 = (e1 < E);
  int d0 = rdi(ei, (long long)E + e0, i64);
  int d1 = h1 ? rdi(ei, (long long)E + e1, i64) : 0;
  float w0 = rdf(ew, e0, f32);
  float w1 = h1 ? rdf(ew, e1, f32) : 0.f;
  unsigned r0 = 0u, r1 = 0u;
  if ((unsigned)d0 < (unsigned)N){
    unsigned long long add = (1ull << 44) |
        (unsigned long long)__float2uint_rn(w0 * DEG_SCALE);
    r0 = (unsigned)(atomicAdd(&packed[d0], add) >> 44);
  }
  if (h1 && (unsigned)d1 < (unsigned)N){
    unsigned long long add = (1ull << 44) |
        (unsigned long long)__float2uint_rn(w1 * DEG_SCALE);
    r1 = (unsigned)(atomicAdd(&packed[d1], add) >> 44);
  }
  rank[e0] = r0;
  if (h1) rank[e1] = r1;
}

__device__ __forceinline__ unsigned wave_incl_scan(unsigned v){
  int lane = threadIdx.x & 63;
  #pragma unroll
  for (int d = 1; d < 64; d <<= 1){
    unsigned t = __shfl_up(v, d, 64);
    if (lane >= d) v += t;
  }
  return v;
}

// scan phase A: per-block PADDED-count sum -> bsum; fused dinv + self-weight;
// also prefills epk (grid-stride).
__global__ __launch_bounds__(256) void k_scan_pre(const unsigned long long* __restrict__ packed,
                                                  float* __restrict__ dinv,
                                                  float* __restrict__ swv,
                                                  unsigned* __restrict__ bsum,
                                                  unsigned* __restrict__ epk, unsigned Epad,
                                                  int N){
  __shared__ unsigned wsh[4];
  int tid = threadIdx.x, lane = tid & 63, wid = tid >> 6;
  unsigned gid = blockIdx.x*blockDim.x + tid, gstr = gridDim.x*blockDim.x;
  for (unsigned j = gid; j < Epad; j += gstr) epk[j] = 0u;
  int i0 = blockIdx.x*1024 + tid*4;
  unsigned tsum = 0u;
  #pragma unroll
  for (int j = 0; j < 4; j++){
    int i = i0 + j;
    if (i < N){
      unsigned long long pv = packed[i];
      tsum += ((unsigned)(pv >> 44) + 7u) & ~7u;
      float d = (float)(pv & DEG_MASK) * (1.0f / DEG_SCALE);
      float di = (d > 0.f) ? rsqrtf(d) : 0.f;
      dinv[i] = di;
      swv[i]  = di * di * SELF_W;
    }
  }
  #pragma unroll
  for (int d = 1; d < 64; d <<= 1) tsum += __shfl_down(tsum, d, 64);
  if (lane == 0) wsh[wid] = tsum;
  __syncthreads();
  if (tid == 0) bsum[blockIdx.x] = wsh[0] + wsh[1] + wsh[2] + wsh[3];
}

// scan phase B+C fused.
__global__ __launch_bounds__(256) void k_scan_fin(const unsigned long long* __restrict__ packed,
                                                  const unsigned* __restrict__ bsum,
                                                  unsigned* __restrict__ off, int N, int NB){
  __shared__ unsigned wsh[4];
  __shared__ unsigned sbase, stot;
  int tid = threadIdx.x, lane = tid & 63, wid = tid >> 6;
  if (tid < 64){
    unsigned v = (tid < NB) ? bsum[tid] : 0u;
    unsigned isc = wave_incl_scan(v);
    if (tid == (int)blockIdx.x) sbase = isc - v;
    if (tid == 63) stot = isc;
  }
  __syncthreads();
  int i0 = blockIdx.x*1024 + tid*4;
  unsigned v0=0u,v1=0u,v2=0u,v3=0u;
  if (i0+0 < N) v0 = ((unsigned)(packed[i0+0] >> 44) + 7u) & ~7u;
  if (i0+1 < N) v1 = ((unsigned)(packed[i0+1] >> 44) + 7u) & ~7u;
  if (i0+2 < N) v2 = ((unsigned)(packed[i0+2] >> 44) + 7u) & ~7u;
  if (i0+3 < N) v3 = ((unsigned)(packed[i0+3] >> 44) + 7u) & ~7u;
  unsigned tsum = v0+v1+v2+v3;
  unsigned isc = wave_incl_scan(tsum);
  if (lane == 63) wsh[wid] = isc;
  __syncthreads();
  unsigned wbase = 0u;
  #pragma unroll
  for (int w = 0; w < 4; w++) if (w < wid) wbase += wsh[w];
  unsigned ex = sbase + wbase + (isc - tsum);
  if (i0+0 < N) off[i0+0] = ex;
  if (i0+1 < N) off[i0+1] = ex + v0;
  if (i0+2 < N) off[i0+2] = ex + v0 + v1;
  if (i0+3 < N) off[i0+3] = ex + v0 + v1 + v2;
  if (blockIdx.x == gridDim.x - 1 && tid == 0) off[N] = stot;
}

// edge pass 2: atomic-free scatter; pack (u16 src | fp16 coef)
__global__ void k_bucket(const void* __restrict__ ei, const void* __restrict__ ew,
                         const float* __restrict__ dinv,
                         const unsigned* __restrict__ off,
                         const unsigned* __restrict__ rank,
                         unsigned* __restrict__ epk,
                         int E, unsigned Epad, int N, const int* __restrict__ flags){
  int e0 = 2*(blockIdx.x*blockDim.x + threadIdx.x);
  if (e0 >= E) return;
  int i64 = flags[1], f32 = flags[0];
  #pragma unroll
  for (int j = 0; j < 2; j++){
    int e = e0 + j;
    if (e >= E) break;
    int s_ = rdi(ei, e, i64);
    int d  = rdi(ei, (long long)E + e, i64);
    if ((unsigned)s_ >= (unsigned)N || (unsigned)d >= (unsigned)N) continue;
    unsigned pos = off[d] + rank[e];
    if (pos < Epad){
      float coef = dinv[s_] * rdf(ew, e, f32) * dinv[d];
      _Float16 ch = (_Float16)coef;
      unsigned cu = (unsigned)__builtin_bit_cast(unsigned short, ch);
      epk[pos] = ((unsigned)s_ & 0xffffu) | (cu << 16);
    }
  }
}

// MFMA GEMM: t = in[N,128] @ W; ROW-MAJOR fp16 output [N][128].
// MODE 0: in = raw x dense (flag-aware). MODE 1: in = fp16 row-major [N][128].
template<int MODE>
__global__ __launch_bounds__(256) void k_gemm(const void* __restrict__ in,
                                              const _Float16* __restrict__ WT,
                                              _Float16* __restrict__ outp, int N,
                                              const int* __restrict__ flags){
  __shared__ _Float16 sout[4*16*136];   // [wave][16 rows][128+8 cols]
  int tid  = threadIdx.x;
  int wid  = tid >> 6, lane = tid & 63;
  int ln   = lane & 15, quad = lane >> 4;
  int row0 = blockIdx.x * 64;
  int rowA = row0 + wid*16 + ln;
  int rA   = (rowA < N) ? rowA : (N > 0 ? N-1 : 0);

  half8 af[4];
  if (MODE == 1){
    const _Float16* src = (const _Float16*)in + (size_t)rA*FDIM + quad*8;
    #pragma unroll
    for (int kc = 0; kc < 4; kc++)
      af[kc] = *(const half8*)(src + kc*32);
  } else {
    if (flags[0]){
      const float* src = (const float*)in + (size_t)rA*FDIM + quad*8;
      #pragma unroll
      for (int kc = 0; kc < 4; kc++){
        float4 a = *(const float4*)(src + kc*32);
        float4 b = *(const float4*)(src + kc*32 + 4);
        half8 h; h[0]=(_Float16)a.x; h[1]=(_Float16)a.y; h[2]=(_Float16)a.z; h[3]=(_Float16)a.w;
        h[4]=(_Float16)b.x; h[5]=(_Float16)b.y; h[6]=(_Float16)b.z; h[7]=(_Float16)b.w;
        af[kc] = h;
      }
    } else {
      const unsigned short* src = (const unsigned short*)in + (size_t)rA*FDIM + quad*8;
      #pragma unroll
      for (int kc = 0; kc < 4; kc++){
        ushort4 u0 = *(const ushort4*)(src + kc*32);
        ushort4 u1 = *(const ushort4*)(src + kc*32 + 4);
        half8 h;
        h[0]=(_Float16)__uint_as_float((unsigned)u0.x<<16);
        h[1]=(_Float16)__uint_as_float((unsigned)u0.y<<16);
        h[2]=(_Float16)__uint_as_float((unsigned)u0.z<<16);
        h[3]=(_Float16)__uint_as_float((unsigned)u0.w<<16);
        h[4]=(_Float16)__uint_as_float((unsigned)u1.x<<16);
        h[5]=(_Float16)__uint_as_float((unsigned)u1.y<<16);
        h[6]=(_Float16)__uint_as_float((unsigned)u1.z<<16);
        h[7]=(_Float16)__uint_as_float((unsigned)u1.w<<16);
        af[kc] = h;
      }
    }
  }

  f32x4 acc[8];
  #pragma unroll
  for (int nt = 0; nt < 8; nt++) acc[nt] = (f32x4){0.f,0.f,0.f,0.f};

  #pragma unroll
  for (int kc = 0; kc < 4; kc++){
    #pragma unroll
    for (int nt = 0; nt < 8; nt++){
      half8 bf = *(const half8*)(WT + (size_t)(nt*16 + ln)*FDIM + kc*32 + quad*8);
      acc[nt] = __builtin_amdgcn_mfma_f32_16x16x32_f16(af[kc], bf, acc[nt], 0, 0, 0);
    }
  }

  _Float16* so = sout + wid*2176;
  #pragma unroll
  for (int nt = 0; nt < 8; nt++)
    #pragma unroll
    for (int reg = 0; reg < 4; reg++)
      so[(quad*4 + reg)*136 + nt*16 + ln] = (_Float16)acc[nt][reg];
  __syncthreads();

  #pragma unroll
  for (int c = 0; c < 4; c++){
    int chunk = tid + c*256;
    int r = chunk >> 4, co = (chunk & 15)*8;
    int row = row0 + r;
    if (row < N){
      half8 v = *(const half8*)(sout + (r>>4)*2176 + (r&15)*136 + co);
      *(half8*)(outp + (size_t)row*FDIM + co) = v;   // row-major store
    }
  }
}

// ONE-PASS aggregation (row-major table): wave = 4 nodes, 16 lanes x 8 cols.
__global__ __launch_bounds__(256) void k_agg(const _Float16* __restrict__ tp,
                                             const float* __restrict__ swv,
                                             const unsigned* __restrict__ off,
                                             const unsigned* __restrict__ epk,
                                             const float* __restrict__ bias,
                                             _Float16* __restrict__ hp,
                                             int N){
  int tid  = threadIdx.x;
  int wv   = tid >> 6, lane = tid & 63;
  int quad = lane >> 4, ql = lane & 15;
  int n = blockIdx.x*16 + wv*4 + quad;
  bool valid = (n < N);
  int nn = valid ? n : 0;
  const _Float16* myt = tp + ql*8;     // lane's 8-col slice base

  float acc[8];
  {
    float sw = swv[nn];
    half8 sv = *(const half8*)(myt + (size_t)nn*FDIM);
    #pragma unroll
    for (int k = 0; k < 8; k++) acc[k] = sw * (float)sv[k];
  }

  unsigned beg = off[nn];
  unsigned end = valid ? off[nn+1] : beg;
  if (beg < end){
    uint4 p0 = *(const uint4*)(epk + beg);
    uint4 p1 = *(const uint4*)(epk + beg + 4);
    for (unsigned i = beg; i < end; i += 8){
      unsigned ni  = i + 8;
      unsigned pre = (ni < end) ? ni : beg;     // clamped prefetch (always valid)
      uint4 q0 = *(const uint4*)(epk + pre);
      uint4 q1 = *(const uint4*)(epk + pre + 4);
      unsigned vs[8] = {p0.x,p0.y,p0.z,p0.w,p1.x,p1.y,p1.z,p1.w};
      half8 tv[8];
      #pragma unroll
      for (int j = 0; j < 8; j++)
        tv[j] = *(const half8*)(myt + (size_t)(vs[j] & 0xffffu)*FDIM);
      #pragma unroll
      for (int j = 0; j < 8; j++){
        float w = (float)__builtin_bit_cast(_Float16, (unsigned short)(vs[j] >> 16));
        #pragma unroll
        for (int k = 0; k < 8; k++)
          acc[k] += w * (float)tv[j][k];
      }
      p0 = q0; p1 = q1;
    }
  }
  int cc = ql*8;
  float4 b0 = *(const float4*)(bias + cc);
  float4 b1 = *(const float4*)(bias + cc + 4);
  float bb[8] = {b0.x,b0.y,b0.z,b0.w,b1.x,b1.y,b1.z,b1.w};
  half8 out;
  #pragma unroll
  for (int k = 0; k < 8; k++)
    out[k] = (_Float16)tanh_fast(acc[k] + bb[k]);
  if (valid)
    *(half8*)(hp + (size_t)nn*FDIM + ql*8) = out;
}

// pool stage 1: 16 blocks/graph, deterministic partial slots (row-major hp).
__global__ __launch_bounds__(256) void k_pool_part(const _Float16* __restrict__ hp,
                                                   const unsigned* __restrict__ gstart,
                                                   float* __restrict__ pmax,
                                                   float* __restrict__ psum){
  int g = blockIdx.x >> 4, sub = blockIdx.x & 15;
  int tid = threadIdx.x;
  int col = tid & 127, half_ = tid >> 7;
  const _Float16* hpp = hp + col;
  unsigned s0 = gstart[g], s1 = gstart[g+1];
  float m = -INFINITY, sm = 0.f;
  for (unsigned n = s0 + sub*2 + half_; n < s1; n += 32){
    float v = (float)hpp[(size_t)n*FDIM];
    m = fmaxf(m, v); sm += v;
  }
  __shared__ float shm[256], shs[256];
  shm[tid] = m; shs[tid] = sm;
  __syncthreads();
  if (half_ == 0){
    m  = fmaxf(m, shm[tid + 128]);
    sm += shs[tid + 128];
    int slot = (g*16 + sub)*128 + col;
    pmax[slot] = m;
    psum[slot] = sm;
  }
}

// pool stage 2 + head.
__global__ __launch_bounds__(256) void k_pool_out(const float* __restrict__ pmax,
                                                  const float* __restrict__ psum,
                                                  const unsigned* __restrict__ gstart,
                                                  const float* __restrict__ Wout,
                                                  const float* __restrict__ bout,
                                                  void* __restrict__ outp,
                                                  const int* __restrict__ flags){
  int g = blockIdx.x, tid = threadIdx.x;
  int col = tid & 127, sub = tid >> 7;
  unsigned cnt = gstart[g+1] - gstart[g];
  float val;
  if (sub == 0){
    float m = -INFINITY;
    #pragma unroll
    for (int j = 0; j < 16; j++) m = fmaxf(m, pmax[(g*16 + j)*128 + col]);
    val = (cnt > 0 && m > -INFINITY) ? m : 0.f;
  } else {
    float s = 0.f;
    #pragma unroll
    for (int j = 0; j < 16; j++) s += psum[(g*16 + j)*128 + col];
    val = s / (float)(cnt ? cnt : 1u);
  }
  int hcol = sub*128 + col;
  int f32out = flags[0];
  int hidx = NGRAPH + g*(2*FDIM) + hcol;
  if (f32out) ((float*)outp)[hidx] = val;
  else        ((bf16*)outp)[hidx] = __float2bfloat16(val);

  __shared__ float red[256];
  red[hcol] = val * Wout[hcol];
  __syncthreads();
  for (int s = 128; s > 0; s >>= 1){
    if (tid < s) red[tid] += red[tid + s];
    __syncthreads();
  }
  if (tid == 0){
    float o = red[0] + bout[0];
    if (f32out) ((float*)outp)[g] = o;
    else        ((bf16*)outp)[g] = __float2bfloat16(o);
  }
}

extern "C" void kernel_launch(void* const* d_in, const int* in_sizes, int n_in,
                              void* d_out, int out_size, void* d_ws, size_t ws_size,
                              hipStream_t stream){
  int N = in_sizes[0] / FDIM;   // x: [N,128]
  int E = in_sizes[3];          // edge_weight: [E]
  int NB = (N + 1023) / 1024;
  unsigned Epad = (unsigned)E + 8u*(unsigned)N;

  char* p = (char*)d_ws;
  auto alloc = [&](size_t bytes){ char* r = p; p += (bytes + 255) & ~(size_t)255; return r; };
  int*       flags  = (int*)      alloc(16);
  float*     pf     = (float*)    alloc((size_t)(66305 + 64)*4);
  _Float16*  wt     = (_Float16*) alloc((size_t)4*FDIM*FDIM*2);
  unsigned long long* packed = (unsigned long long*)alloc((size_t)N*8);
  float*     dinv   = (float*)    alloc((size_t)N*4);
  float*     swv    = (float*)    alloc((size_t)N*4);
  unsigned*  off    = (unsigned*) alloc((size_t)(N+1)*4);
  unsigned*  bsum   = (unsigned*) alloc((size_t)128*4);
  unsigned*  rank   = (unsigned*) alloc((size_t)E*4);
  unsigned*  epk    = (unsigned*) alloc((size_t)Epad*4);
  _Float16*  th     = (_Float16*) alloc((size_t)N*FDIM*2);  // row-major [N][128]
  _Float16*  hh     = (_Float16*) alloc((size_t)N*FDIM*2);  // row-major [N][128]
  float*     pmax   = (float*)    alloc((size_t)NGRAPH*16*128*4);
  float*     psum   = (float*)    alloc((size_t)NGRAPH*16*128*4);
  unsigned*  gstart = (unsigned*) alloc((size_t)(NGRAPH+1)*4);

  float* bf_[4] = {pf + 65536, pf + 65664, pf + 65792, pf + 65920};
  float* Woutf  = pf + 66048;
  float* boutf  = pf + 66304;

  PtrPack pk;
  pk.p[0]=d_in[4]; pk.p[1]=d_in[6]; pk.p[2]=d_in[8]; pk.p[3]=d_in[10];
  pk.p[4]=d_in[5]; pk.p[5]=d_in[7]; pk.p[6]=d_in[9]; pk.p[7]=d_in[11];
  pk.p[8]=d_in[12]; pk.p[9]=d_in[13];
  k_setup<<<(66305 + 255)/256, 256, 0, stream>>>(pk, pf, wt, packed, d_in[2], gstart,
                                                 (const unsigned short*)d_in[0],
                                                 (const int*)d_in[1], flags, N);
  int gE2 = (E + 511)/512;
  k_edge_deg<<<gE2, 256, 0, stream>>>(d_in[1], d_in[3], packed, rank, E, N, flags);
  k_scan_pre<<<NB, 256, 0, stream>>>(packed, dinv, swv, bsum, epk, Epad, N);
  k_scan_fin<<<NB, 256, 0, stream>>>(packed, bsum, off, N, NB);
  k_bucket<<<gE2, 256, 0, stream>>>(d_in[1], d_in[3], dinv, off, rank, epk, E, Epad, N, flags);

  int gG = (N + 63)/64;
  int gA = (N + 15)/16;    // one-pass agg: 16 nodes/block, no panel dimension

  k_gemm<0><<<gG, 256, 0, stream>>>(d_in[0], wt + 0*16384, th, N, flags);
  k_agg<<<gA, 256, 0, stream>>>(th, swv, off, epk, bf_[0], hh, N);
  for (int l = 1; l < 4; l++){
    k_gemm<1><<<gG, 256, 0, stream>>>(hh, wt + (size_t)l*16384, th, N, flags);
    k_agg<<<gA, 256, 0, stream>>>(th, swv, off, epk, bf_[l], hh, N);
  }

  k_pool_part<<<16*NGRAPH, 256, 0, stream>>>(hh, gstart, pmax, psum);
  k_pool_out<<<NGRAPH, 256, 0, stream>>>(pmax, psum, gstart, Woutf, boutf, d_out, flags);
}